// Round 1
// baseline (575.040 us; speedup 1.0000x reference)
//
#include <hip/hip_runtime.h>
#include <math.h>

#define NCH   64
#define IMH   512
#define IMW   512
#define NPTS  150000
#define IMHW  (512 * 512)
#define HID   32

__global__ __launch_bounds__(256) void ffd_kernel(
    const float* __restrict__ before,
    const float* __restrict__ after,
    const float* __restrict__ offsets,
    const int*   __restrict__ coords,
    const float* __restrict__ W1,   // [131, 32]
    const float* __restrict__ b1,   // [32]
    const float* __restrict__ W2,   // [32, 3]
    const float* __restrict__ b2,   // [3]
    float*       __restrict__ out)  // [2, 150000, 3]
{
    int gid = blockIdx.x * blockDim.x + threadIdx.x;
    if (gid >= 2 * NPTS) return;

    const int b = (gid >= NPTS) ? 1 : 0;
    const long pbase = (long)gid * 3;

    const int y = coords[pbase + 1];
    const int x = coords[pbase + 2];

    float acc[HID];
    #pragma unroll
    for (int h = 0; h < HID; ++h) acc[h] = b1[h];   // uniform -> s_load broadcast

    const long img_off = (long)b * NCH * IMHW + (long)y * IMW + x;
    const float* bp = before + img_off;
    const float* ap = after  + img_off;

    float g[16];

    // before image: W1 rows 0..63
    for (int cc = 0; cc < NCH; cc += 16) {
        #pragma unroll
        for (int j = 0; j < 16; ++j) g[j] = bp[(long)(cc + j) * IMHW];
        #pragma unroll
        for (int j = 0; j < 16; ++j) {
            const float* wrow = W1 + (cc + j) * HID;   // uniform row
            #pragma unroll
            for (int h = 0; h < HID; ++h) acc[h] = fmaf(g[j], wrow[h], acc[h]);
        }
    }
    // after image: W1 rows 64..127
    for (int cc = 0; cc < NCH; cc += 16) {
        #pragma unroll
        for (int j = 0; j < 16; ++j) g[j] = ap[(long)(cc + j) * IMHW];
        #pragma unroll
        for (int j = 0; j < 16; ++j) {
            const float* wrow = W1 + (64 + cc + j) * HID;
            #pragma unroll
            for (int h = 0; h < HID; ++h) acc[h] = fmaf(g[j], wrow[h], acc[h]);
        }
    }
    // point offsets: W1 rows 128..130
    #pragma unroll
    for (int k = 0; k < 3; ++k) {
        const float v = offsets[pbase + k];
        const float* wrow = W1 + (128 + k) * HID;
        #pragma unroll
        for (int h = 0; h < HID; ++h) acc[h] = fmaf(v, wrow[h], acc[h]);
    }

    // exact GELU: 0.5*x*(1+erf(x/sqrt(2)))
    #pragma unroll
    for (int h = 0; h < HID; ++h) {
        const float xh = acc[h];
        acc[h] = 0.5f * xh * (1.0f + erff(xh * 0.70710678118654752f));
    }

    float o0 = b2[0], o1 = b2[1], o2 = b2[2];
    #pragma unroll
    for (int h = 0; h < HID; ++h) {
        o0 = fmaf(acc[h], W2[h * 3 + 0], o0);
        o1 = fmaf(acc[h], W2[h * 3 + 1], o1);
        o2 = fmaf(acc[h], W2[h * 3 + 2], o2);
    }

    out[pbase + 0] = o0;
    out[pbase + 1] = o1;
    out[pbase + 2] = o2;
}

extern "C" void kernel_launch(void* const* d_in, const int* in_sizes, int n_in,
                              void* d_out, int out_size, void* d_ws, size_t ws_size,
                              hipStream_t stream) {
    const float* before  = (const float*)d_in[0];
    const float* after   = (const float*)d_in[1];
    const float* offsets = (const float*)d_in[2];
    const int*   coords  = (const int*)  d_in[3];
    const float* W1      = (const float*)d_in[4];
    const float* b1      = (const float*)d_in[5];
    const float* W2      = (const float*)d_in[6];
    const float* b2      = (const float*)d_in[7];
    float* out = (float*)d_out;

    const int total  = 2 * NPTS;
    const int block  = 256;
    const int grid   = (total + block - 1) / block;
    ffd_kernel<<<grid, block, 0, stream>>>(before, after, offsets, coords,
                                           W1, b1, W2, b2, out);
}

// Round 2
// 112.658 us; speedup vs baseline: 5.1043x; 5.1043x over previous
//
#include <hip/hip_runtime.h>
#include <math.h>

#define NCH   64
#define IMW   512
#define NPTS  150000
#define TOTAL (2 * NPTS)
#define IMHW  (512 * 512)
#define HID   32
#define NBINS 32768   // 2 batches x 512 y x 32 x-cells (16 px = one 64B line)

// ---------- sort pass ----------

__global__ __launch_bounds__(256) void hist_kernel(const int* __restrict__ coords,
                                                   int* __restrict__ hist) {
    int gid = blockIdx.x * blockDim.x + threadIdx.x;
    if (gid >= TOTAL) return;
    const int y = coords[gid * 3 + 1];
    const int x = coords[gid * 3 + 2];
    const int b = (gid >= NPTS) ? 1 : 0;
    const int key = (b << 14) | (y << 5) | (x >> 4);
    atomicAdd(&hist[key], 1);
}

// single-block exclusive scan of 32768 ints (1024 thr x 32 each)
__global__ __launch_bounds__(1024) void scan_kernel(const int* __restrict__ hist,
                                                    int* __restrict__ binPos) {
    __shared__ int lds[1024];
    const int t = threadIdx.x;
    const int base = t * 32;
    int loc[32];
    int s = 0;
    #pragma unroll
    for (int i = 0; i < 32; ++i) { loc[i] = s; s += hist[base + i]; }
    lds[t] = s;
    __syncthreads();
    // Hillis-Steele inclusive scan over 1024 chunk sums
    for (int d = 1; d < 1024; d <<= 1) {
        int v = lds[t];
        int add = (t >= d) ? lds[t - d] : 0;
        __syncthreads();
        lds[t] = v + add;
        __syncthreads();
    }
    const int excl = lds[t] - s;   // exclusive prefix of this chunk
    #pragma unroll
    for (int i = 0; i < 32; ++i) binPos[base + i] = excl + loc[i];
}

__global__ __launch_bounds__(256) void scatter_kernel(const int* __restrict__ coords,
                                                      int* __restrict__ binPos,
                                                      int* __restrict__ perm) {
    int gid = blockIdx.x * blockDim.x + threadIdx.x;
    if (gid >= TOTAL) return;
    const int y = coords[gid * 3 + 1];
    const int x = coords[gid * 3 + 2];
    const int b = (gid >= NPTS) ? 1 : 0;
    const int key = (b << 14) | (y << 5) | (x >> 4);
    const int pos = atomicAdd(&binPos[key], 1);
    perm[pos] = gid;
}

// ---------- fused gather + MLP ----------

__global__ __launch_bounds__(256) void ffd_kernel(
    const float* __restrict__ before,
    const float* __restrict__ after,
    const float* __restrict__ offsets,
    const int*   __restrict__ coords,
    const float* __restrict__ W1,   // [131, 32]
    const float* __restrict__ b1,   // [32]
    const float* __restrict__ W2,   // [32, 3]
    const float* __restrict__ b2,   // [3]
    const int*   __restrict__ perm, // sorted point order (or null)
    float*       __restrict__ out)  // [2, 150000, 3]
{
    int gid = blockIdx.x * blockDim.x + threadIdx.x;
    if (gid >= TOTAL) return;
    const int pid = perm ? perm[gid] : gid;

    const int b = (pid >= NPTS) ? 1 : 0;
    const long pbase = (long)pid * 3;

    const int y = coords[pbase + 1];
    const int x = coords[pbase + 2];

    float acc[HID];
    #pragma unroll
    for (int h = 0; h < HID; ++h) acc[h] = b1[h];   // uniform -> scalar broadcast

    const long img_off = (long)b * NCH * IMHW + (long)y * IMW + x;
    const float* bp = before + img_off;
    const float* ap = after  + img_off;

    float g[16];

    // before image: W1 rows 0..63
    for (int cc = 0; cc < NCH; cc += 16) {
        #pragma unroll
        for (int j = 0; j < 16; ++j) g[j] = bp[(long)(cc + j) * IMHW];
        #pragma unroll
        for (int j = 0; j < 16; ++j) {
            const float* wrow = W1 + (cc + j) * HID;
            #pragma unroll
            for (int h = 0; h < HID; ++h) acc[h] = fmaf(g[j], wrow[h], acc[h]);
        }
    }
    // after image: W1 rows 64..127
    for (int cc = 0; cc < NCH; cc += 16) {
        #pragma unroll
        for (int j = 0; j < 16; ++j) g[j] = ap[(long)(cc + j) * IMHW];
        #pragma unroll
        for (int j = 0; j < 16; ++j) {
            const float* wrow = W1 + (64 + cc + j) * HID;
            #pragma unroll
            for (int h = 0; h < HID; ++h) acc[h] = fmaf(g[j], wrow[h], acc[h]);
        }
    }
    // point offsets: W1 rows 128..130
    #pragma unroll
    for (int k = 0; k < 3; ++k) {
        const float v = offsets[pbase + k];
        const float* wrow = W1 + (128 + k) * HID;
        #pragma unroll
        for (int h = 0; h < HID; ++h) acc[h] = fmaf(v, wrow[h], acc[h]);
    }

    // exact GELU
    #pragma unroll
    for (int h = 0; h < HID; ++h) {
        const float xh = acc[h];
        acc[h] = 0.5f * xh * (1.0f + erff(xh * 0.70710678118654752f));
    }

    float o0 = b2[0], o1 = b2[1], o2 = b2[2];
    #pragma unroll
    for (int h = 0; h < HID; ++h) {
        o0 = fmaf(acc[h], W2[h * 3 + 0], o0);
        o1 = fmaf(acc[h], W2[h * 3 + 1], o1);
        o2 = fmaf(acc[h], W2[h * 3 + 2], o2);
    }

    out[pbase + 0] = o0;
    out[pbase + 1] = o1;
    out[pbase + 2] = o2;
}

extern "C" void kernel_launch(void* const* d_in, const int* in_sizes, int n_in,
                              void* d_out, int out_size, void* d_ws, size_t ws_size,
                              hipStream_t stream) {
    const float* before  = (const float*)d_in[0];
    const float* after   = (const float*)d_in[1];
    const float* offsets = (const float*)d_in[2];
    const int*   coords  = (const int*)  d_in[3];
    const float* W1      = (const float*)d_in[4];
    const float* b1      = (const float*)d_in[5];
    const float* W2      = (const float*)d_in[6];
    const float* b2      = (const float*)d_in[7];
    float* out = (float*)d_out;

    const int block = 256;
    const int grid  = (TOTAL + block - 1) / block;

    // ws layout: hist[NBINS] | binPos[NBINS] | perm[TOTAL]
    const size_t need = (size_t)(2 * NBINS + TOTAL) * sizeof(int);

    if (ws_size >= need) {
        int* hist   = (int*)d_ws;
        int* binPos = hist + NBINS;
        int* perm   = binPos + NBINS;

        hipMemsetAsync(hist, 0, NBINS * sizeof(int), stream);
        hist_kernel<<<grid, block, 0, stream>>>(coords, hist);
        scan_kernel<<<1, 1024, 0, stream>>>(hist, binPos);
        scatter_kernel<<<grid, block, 0, stream>>>(coords, binPos, perm);
        ffd_kernel<<<grid, block, 0, stream>>>(before, after, offsets, coords,
                                               W1, b1, W2, b2, perm, out);
    } else {
        ffd_kernel<<<grid, block, 0, stream>>>(before, after, offsets, coords,
                                               W1, b1, W2, b2, nullptr, out);
    }
}